// Round 16
// baseline (331.457 us; speedup 1.0000x reference)
//
#include <hip/hip_runtime.h>
#include <hip/hip_bf16.h>
#include <cstdint>
#include <cstddef>

typedef short bf16x8 __attribute__((ext_vector_type(8)));
typedef float f32x4 __attribute__((ext_vector_type(4)));

__device__ __forceinline__ void gload_lds16(const void* g, void* l) {
  __builtin_amdgcn_global_load_lds((__attribute__((address_space(1))) const void*)g,
                                   (__attribute__((address_space(3))) void*)l, 16, 0, 0);
}

__device__ __forceinline__ unsigned short f2bf(float f) {
  unsigned u = __builtin_bit_cast(unsigned, f);
  u += 0x7fffu + ((u >> 16) & 1u);
  return (unsigned short)(u >> 16);
}
__device__ __forceinline__ float bf2f(unsigned short h) {
  unsigned u = ((unsigned)h) << 16;
  return __builtin_bit_cast(float, u);
}

// ------- casts needed BEFORE the QKV GEMM (x, wqkv, wvkv, vis) -------------
struct CastPack {
  const float* s[6];
  unsigned short* d[6];
  int n4[6];
};
__global__ void k_cast_all(CastPack p) {
  const int tid0 = blockIdx.x * blockDim.x + threadIdx.x;
  const int stride = gridDim.x * blockDim.x;
#pragma unroll 1
  for (int seg = 0; seg < 6; ++seg) {
    const float4* __restrict__ src = reinterpret_cast<const float4*>(p.s[seg]);
    ushort4* __restrict__ dst = reinterpret_cast<ushort4*>(p.d[seg]);
    const int n4 = p.n4[seg];
    for (int i = tid0; i < n4; i += stride) {
      float4 v = src[i];
      ushort4 o;
      o.x = f2bf(v.x); o.y = f2bf(v.y); o.z = f2bf(v.z); o.w = f2bf(v.w);
      dst[i] = o;
    }
  }
}

__device__ __forceinline__ void storeC(float* C, size_t i, float v) { C[i] = v; }
__device__ __forceinline__ void storeC(unsigned short* C, size_t i, float v) { C[i] = f2bf(v); }

// ---------------- 256x128 pipelined GEMM, single-barrier phases ------------
// (r9-verified structure; ldC-aware so it can write a column slice of qkv)
template <typename OutT>
__global__ __launch_bounds__(512) void k_gemm256x128(
    const unsigned short* __restrict__ A,
    const unsigned short* __restrict__ B,
    OutT* __restrict__ C,
    int M, int N, int K, int ldC) {
  __shared__ __align__(16) unsigned short lA[2][2][256][32];
  __shared__ __align__(16) unsigned short lB[2][2][128][32];
  const int tid = threadIdx.x;
  const int w = tid >> 6, l = tid & 63;
  const int wr = w >> 2, wc = w & 3;
  const int lq = l & 15, g = l >> 4;
  const int fslot = (g ^ ((lq >> 1) & 3)) << 3;

  const int gm = M >> 8, gn = N >> 7;
  const int L = (int)blockIdx.x;
  const int xcd = L & 7, slot = L >> 3;
  const int m0 = (slot % gm) * 256;
  const int n0 = (xcd * (gn >> 3) + slot / gm) * 128;

  const unsigned short* Ap = A + (size_t)m0 * K;
  const unsigned short* Bp = B + (size_t)n0 * K;

  f32x4 acc[8][2];
#pragma unroll
  for (int i = 0; i < 8; ++i)
#pragma unroll
    for (int j = 0; j < 2; ++j) acc[i][j] = f32x4{0.f, 0.f, 0.f, 0.f};

  auto stageA = [&](unsigned short* lbase, int kcol) {
#pragma unroll
    for (int p = 0; p < 2; ++p) {
      int R = w * 32 + p * 16;
      int row = R + (l >> 2);
      int cc = ((l & 3) ^ ((l >> 3) & 3)) << 3;
      gload_lds16(Ap + (size_t)row * K + kcol + cc, lbase + R * 32);
    }
  };
  auto stageB = [&](unsigned short* lbase, int kcol) {
    int R = w * 16;
    int row = R + (l >> 2);
    int cc = ((l & 3) ^ ((l >> 3) & 3)) << 3;
    gload_lds16(Bp + (size_t)row * K + kcol + cc, lbase + R * 32);
  };

  const int nt = K >> 6;

  stageB(&lB[0][0][0][0], 0);
  stageA(&lA[0][0][0][0], 0);
  stageB(&lB[0][1][0][0], 32);
  stageA(&lA[0][1][0][0], 32);
  stageB(&lB[1][0][0][0], 64);
  stageA(&lA[1][0][0][0], 64);
  asm volatile("s_waitcnt vmcnt(3)" ::: "memory");
  __builtin_amdgcn_s_barrier();

  bf16x8 bfr[2], a[8];

  for (int T = 0; T < nt; ++T) {
    const int bf = T & 1, nb = bf ^ 1;

    // ---- phase 1: kk0 ----
#pragma unroll
    for (int nf = 0; nf < 2; ++nf)
      bfr[nf] = *(const bf16x8*)&lB[bf][0][wc * 32 + nf * 16 + lq][fslot];
#pragma unroll
    for (int mf = 0; mf < 8; ++mf)
      a[mf] = *(const bf16x8*)&lA[bf][0][wr * 128 + mf * 16 + lq][fslot];
    if (T + 1 < nt) {
      stageA(&lA[nb][1][0][0], ((T + 1) << 6) + 32);
      stageB(&lB[nb][1][0][0], ((T + 1) << 6) + 32);
    }
    asm volatile("s_waitcnt lgkmcnt(0)" ::: "memory");
    __builtin_amdgcn_s_setprio(1);
#pragma unroll
    for (int mf = 0; mf < 8; ++mf)
#pragma unroll
      for (int nf = 0; nf < 2; ++nf)
        acc[mf][nf] = __builtin_amdgcn_mfma_f32_16x16x32_bf16(a[mf], bfr[nf], acc[mf][nf], 0, 0, 0);
    __builtin_amdgcn_s_setprio(0);
    __builtin_amdgcn_s_barrier();

    // ---- phase 2: kk1 ----
#pragma unroll
    for (int nf = 0; nf < 2; ++nf)
      bfr[nf] = *(const bf16x8*)&lB[bf][1][wc * 32 + nf * 16 + lq][fslot];
#pragma unroll
    for (int mf = 0; mf < 8; ++mf)
      a[mf] = *(const bf16x8*)&lA[bf][1][wr * 128 + mf * 16 + lq][fslot];
    if (T + 2 < nt) {
      stageA(&lA[bf][0][0][0], (T + 2) << 6);
      stageB(&lB[bf][0][0][0], (T + 2) << 6);
    }
    asm volatile("s_waitcnt lgkmcnt(0)" ::: "memory");
    __builtin_amdgcn_s_setprio(1);
#pragma unroll
    for (int mf = 0; mf < 8; ++mf)
#pragma unroll
      for (int nf = 0; nf < 2; ++nf)
        acc[mf][nf] = __builtin_amdgcn_mfma_f32_16x16x32_bf16(a[mf], bfr[nf], acc[mf][nf], 0, 0, 0);
    __builtin_amdgcn_s_setprio(0);
    if (T < nt - 2)
      asm volatile("s_waitcnt vmcnt(3)" ::: "memory");
    else if (T == nt - 2)
      asm volatile("s_waitcnt vmcnt(0)" ::: "memory");
    __builtin_amdgcn_s_barrier();
  }

#pragma unroll
  for (int mf = 0; mf < 8; ++mf)
#pragma unroll
    for (int nf = 0; nf < 2; ++nf) {
      int row = m0 + wr * 128 + mf * 16 + g * 4;
      int col = n0 + wc * 32 + nf * 16 + lq;
#pragma unroll
      for (int r = 0; r < 4; ++r)
        storeC(C, (size_t)(row + r) * ldC + col, acc[mf][nf][r]);
    }
}

// ------- KV-proj + vision GEMM (m97 128²) + wo-cast tail -------------------
// blocks 0..159: GEMM tiles (128 KV-proj + 32 vision, bijective XCD swizzle)
// blocks 160..2047: grid-stride cast of wo f32->bf16. 1888 cast blocks give
// ~7 extra waves/CU of streaming TLP (r15's 256-block tail starved at 1
// block/CU -> 1.6 TB/s); they co-fill CUs alongside the 160 GEMM blocks.
__global__ __launch_bounds__(256) void k_gemm_kv(
    const unsigned short* __restrict__ xb,
    const unsigned short* __restrict__ wkvb,   // wqkvb + 4096*4096 (wk|wv)
    unsigned short* __restrict__ qkv_kv,       // qkv + 4096 (col offset)
    const unsigned short* __restrict__ visb,
    const unsigned short* __restrict__ wvkvb,
    unsigned short* __restrict__ vkvb,
    const float* __restrict__ wo_f32,
    unsigned short* __restrict__ wob) {
  __shared__ __align__(16) unsigned short lA[128 * 64];
  __shared__ __align__(16) unsigned short lB[128 * 64];
  const int orig = (int)blockIdx.x;

  if (orig >= 160) {  // ---- wo cast tail (1888 blocks) ----
    const float4* __restrict__ src = reinterpret_cast<const float4*>(wo_f32);
    ushort4* __restrict__ dst = reinterpret_cast<ushort4*>(wob);
    const int n4 = 4096 * 4096 / 4;
    const int stride = 1888 * 256;
    for (int i = (orig - 160) * 256 + (int)threadIdx.x; i < n4; i += stride) {
      float4 v = src[i];
      ushort4 o;
      o.x = f2bf(v.x); o.y = f2bf(v.y); o.z = f2bf(v.z); o.w = f2bf(v.w);
      dst[i] = o;
    }
    return;
  }

  const int tid = threadIdx.x;
  const int w = tid >> 6, l = tid & 63;
  const int tile = (orig & 7) * 20 + (orig >> 3);   // bijective, 160 = 8*20

  const unsigned short* A;
  const unsigned short* B;
  unsigned short* C;
  int K, ldC, m0, n0;
  if (tile < 128) {          // KV projection: 2048 x 1024 x 4096
    A = xb; B = wkvb; C = qkv_kv; K = 4096; ldC = 5120;
    m0 = (tile & 15) * 128;
    n0 = (tile >> 4) * 128;
  } else {                   // vision: 512 x 1024 x 768
    int v = tile - 128;
    A = visb; B = wvkvb; C = vkvb; K = 768; ldC = 1024;
    m0 = (v & 3) * 128;
    n0 = (v >> 2) * 128;
  }
  const int wm = (w >> 1) * 64, wn = (w & 1) * 64;

  f32x4 acc[4][4];
#pragma unroll
  for (int i = 0; i < 4; ++i)
#pragma unroll
    for (int j = 0; j < 4; ++j) acc[i][j] = f32x4{0.f, 0.f, 0.f, 0.f};

  char* lAc = (char*)lA;
  char* lBc = (char*)lB;

  for (int k0 = 0; k0 < K; k0 += 64) {
#pragma unroll
    for (int p = 0; p < 4; ++p) {
      int r = (w * 4 + p) * 8 + (l >> 3);
      int c = (l & 7) ^ (r & 7);
      gload_lds16(A + (size_t)(m0 + r) * K + k0 + c * 8, lAc + (w * 4 + p) * 1024);
      gload_lds16(B + (size_t)(n0 + r) * K + k0 + c * 8, lBc + (w * 4 + p) * 1024);
    }
    __syncthreads();
#pragma unroll
    for (int kk = 0; kk < 2; ++kk) {
      bf16x8 af[4], bfr[4];
#pragma unroll
      for (int i = 0; i < 4; ++i) {
        int r = wm + i * 16 + (l & 15);
        int slot = (kk * 4 + (l >> 4)) ^ (r & 7);
        af[i] = *(const bf16x8*)(lAc + r * 128 + slot * 16);
      }
#pragma unroll
      for (int j = 0; j < 4; ++j) {
        int r = wn + j * 16 + (l & 15);
        int slot = (kk * 4 + (l >> 4)) ^ (r & 7);
        bfr[j] = *(const bf16x8*)(lBc + r * 128 + slot * 16);
      }
#pragma unroll
      for (int i = 0; i < 4; ++i)
#pragma unroll
        for (int j = 0; j < 4; ++j)
          acc[i][j] = __builtin_amdgcn_mfma_f32_16x16x32_bf16(af[i], bfr[j], acc[i][j], 0, 0, 0);
    }
    __syncthreads();
  }

#pragma unroll
  for (int i = 0; i < 4; ++i)
#pragma unroll
    for (int j = 0; j < 4; ++j) {
      int row = m0 + wm + i * 16 + (l >> 4) * 4;
      int col = n0 + wn + j * 16 + (l & 15);
#pragma unroll
      for (int r = 0; r < 4; ++r)
        storeC(C, (size_t)(row + r) * ldC + col, acc[i][j][r]);
    }
}

// ------- post pass: build K (+RoPE) and build V^T ---------------------------
__global__ void k_post(const unsigned short* __restrict__ qkv,   // [2048][5120]
                       const unsigned short* __restrict__ vkv,   // [512][1024]
                       const float* __restrict__ cosT, const float* __restrict__ sinT,
                       unsigned short* __restrict__ k_all,  // [8][1280][128]
                       unsigned short* __restrict__ v_t) {  // [8][128][1280]
  int idx = blockIdx.x * blockDim.x + threadIdx.x;
  if (idx < 655360) {
    int i = idx;
    int d0 = i & 63;
    int t = (i >> 6) % 1280;
    int bg = i / (64 * 1280);
    int b = bg >> 2, g = bg & 3;
    float a, bb;
    if (t < 256) {
      const unsigned short* src = vkv + (size_t)(b * 256 + t) * 1024 + g * 128;
      a = bf2f(src[d0]); bb = bf2f(src[d0 + 64]);
    } else {
      const unsigned short* src = qkv + (size_t)(b * 1024 + t - 256) * 5120 + 4096 + g * 128;
      a = bf2f(src[d0]); bb = bf2f(src[d0 + 64]);
    }
    float c0 = cosT[t * 128 + d0], s0 = sinT[t * 128 + d0];
    float c1 = cosT[t * 128 + d0 + 64], s1 = sinT[t * 128 + d0 + 64];
    unsigned short* dst = k_all + ((size_t)bg * 1280 + t) * 128;
    dst[d0] = f2bf(a * c0 - bb * s0);
    dst[d0 + 64] = f2bf(bb * c1 + a * s1);
  } else {
    int i = idx - 655360;
    int t = i % 1280;
    int d = (i / 1280) & 127;
    int bg = i / (1280 * 128);
    int b = bg >> 2, g = bg & 3;
    unsigned short v;
    if (t < 256) v = vkv[(size_t)(b * 256 + t) * 1024 + 512 + g * 128 + d];
    else         v = qkv[(size_t)(b * 1024 + t - 256) * 5120 + 4608 + g * 128 + d];
    v_t[(size_t)bg * 128 * 1280 + (size_t)d * 1280 + t] = v;
  }
}

// --------- flash attention: paired q-tiles + on-the-fly RoPE(Q) ------------
__global__ __launch_bounds__(256) void k_attn(
    const unsigned short* __restrict__ qr,     // [2048][5120] un-roped (cols 0..4095)
    const unsigned short* __restrict__ k_all,  // [8][1280][128]
    const unsigned short* __restrict__ v_t,    // [8][128][1280]
    const float* __restrict__ cosT, const float* __restrict__ sinT,
    unsigned short* __restrict__ attn) {       // [2048][4096]
  __shared__ __align__(16) unsigned short lK[2][64 * 128];
  __shared__ __align__(16) unsigned short lV[2][128 * 64];
  __shared__ __align__(16) unsigned short lPT[4][16][72];

  const int tid = threadIdx.x, w = tid >> 6, l = tid & 63;
  const int lq = l & 15, g = l >> 4;
  const int qpair = blockIdx.x;
  const int h = blockIdx.y, b = blockIdx.z;
  const int bg = b * 4 + (h >> 3);
  const unsigned short* kg = k_all + (size_t)bg * 1280 * 128;
  const unsigned short* vg = v_t + (size_t)bg * 128 * 1280;

  char* lKc = (char*)lK;
  char* lVc = (char*)lV;
  char* pbuf = (char*)&lPT[w][0][0];

  auto stage = [&](int t0, int bufsel) {
#pragma unroll
    for (int p = 0; p < 4; ++p) {  // K tile [64][128]
      int r = (w * 4 + p) * 4 + (l >> 4);
      int c = (l & 15) ^ (r & 7);
      gload_lds16(kg + (size_t)(t0 + r) * 128 + c * 8,
                  lKc + bufsel * 16384 + (w * 4 + p) * 1024);
    }
#pragma unroll
    for (int p = 0; p < 4; ++p) {  // V tile [128][64]
      int d = (w * 4 + p) * 8 + (l >> 3);
      int c = (l & 7) ^ (d & 7);
      gload_lds16(vg + (size_t)d * 1280 + t0 + c * 8,
                  lVc + bufsel * 16384 + (w * 4 + p) * 1024);
    }
  };

  int buf = 0;
#pragma unroll 1
  for (int half = 0; half < 2; ++half) {
    const int qb = (half ? (15 - qpair) : qpair) * 64;
    const int qrow_l = qb + w * 16 + lq;
    const int nIter = (qb + 320) >> 6;

    bf16x8 aq[4];
    {
      int row = qb + w * 16 + lq;
      const unsigned short* p = qr + (size_t)(b * 1024 + row) * 5120 + h * 128 + g * 8;
      bf16x8 r0 = *(const bf16x8*)(p);
      bf16x8 r1 = *(const bf16x8*)(p + 32);
      bf16x8 r2 = *(const bf16x8*)(p + 64);
      bf16x8 r3 = *(const bf16x8*)(p + 96);
      const float* cp = cosT + (size_t)row * 128;
      const float* sp = sinT + (size_t)row * 128;
      const float sc = 0.08838834764831845f;  // 128^-0.5
#pragma unroll
      for (int j = 0; j < 8; ++j) {
        int d0 = g * 8 + j;
        float a0 = bf2f((unsigned short)r0[j]), b0 = bf2f((unsigned short)r2[j]);
        aq[0][j] = (short)f2bf((a0 * cp[d0] - b0 * sp[d0]) * sc);
        aq[2][j] = (short)f2bf((b0 * cp[d0 + 64] + a0 * sp[d0 + 64]) * sc);
        int d1 = 32 + g * 8 + j;
        float a1 = bf2f((unsigned short)r1[j]), b1 = bf2f((unsigned short)r3[j]);
        aq[1][j] = (short)f2bf((a1 * cp[d1] - b1 * sp[d1]) * sc);
        aq[3][j] = (short)f2bf((b1 * cp[d1 + 64] + a1 * sp[d1 + 64]) * sc);
      }
    }

    f32x4 o[8];
#pragma unroll
    for (int i = 0; i < 8; ++i) o[i] = f32x4{0.f, 0.f, 0.f, 0.f};
    float mr = -1e30f;
    float lrp = 0.f;

    stage(0, buf);
    __syncthreads();

    for (int it = 0; it < nIter; ++it) {
      const int t0 = it << 6;
      if (it + 1 < nIter) stage(t0 + 64, buf ^ 1);

      const char* kbase = lKc + buf * 16384;
      const char* vbase = lVc + buf * 16384;

      f32x4 sT[4];
      __builtin_amdgcn_s_setprio(1);
#pragma unroll
      for (int sub = 0; sub < 4; ++sub) {
        f32x4 s4 = {0.f, 0.f, 0.f, 0.f};
        int krow = sub * 16 + lq;
        const char* kb = kbase + krow * 256;
#pragma unroll
        for (int kk = 0; kk < 4; ++kk) {
          int slot = (kk * 4 + g) ^ (krow & 7);
          bf16x8 kf = *(const bf16x8*)(kb + slot * 16);
          s4 = __builtin_amdgcn_mfma_f32_16x16x32_bf16(kf, aq[kk], s4, 0, 0, 0);
        }
        sT[sub] = s4;
      }
      __builtin_amdgcn_s_setprio(0);

      if (t0 + 63 > qb + w * 16 + 256) {
#pragma unroll
        for (int sub = 0; sub < 4; ++sub)
#pragma unroll
          for (int r = 0; r < 4; ++r) {
            int t = t0 + sub * 16 + 4 * g + r;
            if (t > qrow_l + 256) sT[sub][r] = -1e30f;
          }
      }

      float pm = fmaxf(fmaxf(fmaxf(sT[0][0], sT[0][1]), fmaxf(sT[0][2], sT[0][3])),
                       fmaxf(fmaxf(sT[1][0], sT[1][1]), fmaxf(sT[1][2], sT[1][3])));
      pm = fmaxf(pm, fmaxf(fmaxf(fmaxf(sT[2][0], sT[2][1]), fmaxf(sT[2][2], sT[2][3])),
                           fmaxf(fmaxf(sT[3][0], sT[3][1]), fmaxf(sT[3][2], sT[3][3]))));
      pm = fmaxf(pm, __shfl_xor(pm, 16));
      pm = fmaxf(pm, __shfl_xor(pm, 32));

      if (!__all(pm <= mr + 8.0f)) {
        float mnew = fmaxf(mr, pm);
        float scl = __expf(mr - mnew);
        mr = mnew;
        lrp *= scl;
        float s0 = __shfl(scl, 4 * g + 0);
        float s1 = __shfl(scl, 4 * g + 1);
        float s2 = __shfl(scl, 4 * g + 2);
        float s3 = __shfl(scl, 4 * g + 3);
#pragma unroll
        for (int cs = 0; cs < 8; ++cs) {
          o[cs][0] *= s0; o[cs][1] *= s1; o[cs][2] *= s2; o[cs][3] *= s3;
        }
      }

#pragma unroll
      for (int sub = 0; sub < 4; ++sub) {
        float p0 = __expf(sT[sub][0] - mr);
        float p1 = __expf(sT[sub][1] - mr);
        float p2 = __expf(sT[sub][2] - mr);
        float p3 = __expf(sT[sub][3] - mr);
        lrp += (p0 + p1) + (p2 + p3);
        unsigned pk0, pk1;
        asm("v_cvt_pk_bf16_f32 %0, %1, %2" : "=v"(pk0) : "v"(p0), "v"(p1));
        asm("v_cvt_pk_bf16_f32 %0, %1, %2" : "=v"(pk1) : "v"(p2), "v"(p3));
        int c = (2 * sub + (g >> 1)) ^ (lq & 7);
        *(uint2*)(pbuf + lq * 144 + c * 16 + (g & 1) * 8) = make_uint2(pk0, pk1);
      }

      asm volatile("s_waitcnt lgkmcnt(0)" ::: "memory");

      bf16x8 pa0 = *(const bf16x8*)(pbuf + lq * 144 + ((g ^ (lq & 7)) * 16));
      bf16x8 pa1 = *(const bf16x8*)(pbuf + lq * 144 + (((4 + g) ^ (lq & 7)) * 16));

      __builtin_amdgcn_s_setprio(1);
#pragma unroll
      for (int cs = 0; cs < 8; ++cs) {
        int drow = cs * 16 + lq;
        const char* vb = vbase + drow * 128;
        int s0i = g ^ (drow & 7);
        int s1i = (4 + g) ^ (drow & 7);
        bf16x8 v0 = *(const bf16x8*)(vb + s0i * 16);
        bf16x8 v1 = *(const bf16x8*)(vb + s1i * 16);
        o[cs] = __builtin_amdgcn_mfma_f32_16x16x32_bf16(pa0, v0, o[cs], 0, 0, 0);
        o[cs] = __builtin_amdgcn_mfma_f32_16x16x32_bf16(pa1, v1, o[cs], 0, 0, 0);
      }
      __builtin_amdgcn_s_setprio(0);

      __syncthreads();
      buf ^= 1;
    }

    lrp += __shfl_xor(lrp, 16);
    lrp += __shfl_xor(lrp, 32);
    float inv = 1.0f / lrp;
    float invr[4];
    invr[0] = __shfl(inv, 4 * g + 0);
    invr[1] = __shfl(inv, 4 * g + 1);
    invr[2] = __shfl(inv, 4 * g + 2);
    invr[3] = __shfl(inv, 4 * g + 3);
#pragma unroll
    for (int cs = 0; cs < 8; ++cs)
#pragma unroll
      for (int r = 0; r < 4; ++r) {
        int row = qb + w * 16 + 4 * g + r;
        attn[(size_t)(b * 1024 + row) * 4096 + h * 128 + cs * 16 + lq] =
            f2bf(o[cs][r] * invr[r]);
      }
  }
}

// ---------------- launcher ----------------
extern "C" void kernel_launch(void* const* d_in, const int* in_sizes, int n_in,
                              void* d_out, int out_size, void* d_ws, size_t ws_size,
                              hipStream_t stream) {
  const float* x    = (const float*)d_in[0];
  const float* vis  = (const float*)d_in[1];
  const float* wq   = (const float*)d_in[2];
  const float* wk   = (const float*)d_in[3];
  const float* wv   = (const float*)d_in[4];
  const float* wo   = (const float*)d_in[5];
  const float* wvkv = (const float*)d_in[6];
  const float* cosT = (const float*)d_in[7];
  const float* sinT = (const float*)d_in[8];
  float* out = (float*)d_out;
  char* ws = (char*)d_ws;

  size_t off = 0;
  auto alloc = [&](size_t b) { size_t r = off; off += (b + 255) & ~(size_t)255; return r; };
  unsigned short* wqkvb = (unsigned short*)(ws + alloc((size_t)5120 * 4096 * 2));  // wq|wk|wv
  unsigned short* wob   = (unsigned short*)(ws + alloc((size_t)4096 * 4096 * 2));
  unsigned short* wvkvb = (unsigned short*)(ws + alloc((size_t)1024 * 768 * 2));
  unsigned short* visb  = (unsigned short*)(ws + alloc((size_t)512 * 768 * 2));
  unsigned short* xb    = (unsigned short*)(ws + alloc((size_t)2048 * 4096 * 2));
  unsigned short* qkv   = (unsigned short*)(ws + alloc((size_t)2048 * 5120 * 2));
  unsigned short* vkvb  = (unsigned short*)(ws + alloc((size_t)512 * 1024 * 2));
  unsigned short* kall  = (unsigned short*)(ws + alloc((size_t)8 * 1280 * 128 * 2));
  unsigned short* vt    = (unsigned short*)(ws + alloc((size_t)8 * 128 * 1280 * 2));
  unsigned short* attnb = xb;  // x is dead after the projections; reuse
  if (ws_size < off) return;

  CastPack cp;
  cp.s[0] = x;    cp.d[0] = xb;                           cp.n4[0] = 2048 * 4096 / 4;
  cp.s[1] = wq;   cp.d[1] = wqkvb;                        cp.n4[1] = 4096 * 4096 / 4;
  cp.s[2] = wk;   cp.d[2] = wqkvb + (size_t)4096 * 4096;  cp.n4[2] = 512 * 4096 / 4;
  cp.s[3] = wv;   cp.d[3] = wqkvb + (size_t)4608 * 4096;  cp.n4[3] = 512 * 4096 / 4;
  cp.s[4] = wvkv; cp.d[4] = wvkvb;                        cp.n4[4] = 1024 * 768 / 4;
  cp.s[5] = vis;  cp.d[5] = visb;                         cp.n4[5] = 512 * 768 / 4;
  k_cast_all<<<dim3(2048), dim3(256), 0, stream>>>(cp);

  // Q projection: de-fenced 256x128 pipelined, 256 blocks = 1/CU full fill
  k_gemm256x128<unsigned short><<<dim3(256), dim3(512), 0, stream>>>(
      xb, wqkvb, qkv, 2048, 4096, 4096, 5120);

  // KV + vision projections (160 m97 tiles) + wo-cast tail (1888 blocks)
  k_gemm_kv<<<dim3(2048), dim3(256), 0, stream>>>(
      xb, wqkvb + (size_t)4096 * 4096, qkv + 4096, visb, wvkvb, vkvb, wo, wob);

  // build K (+RoPE) and V^T (Q rope is fused into attention)
  k_post<<<dim3(7680), dim3(256), 0, stream>>>(qkv, vkvb, cosT, sinT, kall, vt);

  // paired-tile attention: 512 blocks, uniform work, on-the-fly Q rope
  k_attn<<<dim3(8, 32, 2), dim3(256), 0, stream>>>(qkv, kall, vt, cosT, sinT, attnb);

  // out projection (de-fenced 256x128 pipelined, 256 blocks)
  k_gemm256x128<float><<<dim3(256), dim3(512), 0, stream>>>(
      attnb, wob, out, 2048, 4096, 4096, 4096);
}

// Round 17
// 291.429 us; speedup vs baseline: 1.1374x; 1.1374x over previous
//
#include <hip/hip_runtime.h>
#include <hip/hip_bf16.h>
#include <cstdint>
#include <cstddef>

typedef short bf16x8 __attribute__((ext_vector_type(8)));
typedef float f32x4 __attribute__((ext_vector_type(4)));

__device__ __forceinline__ void gload_lds16(const void* g, void* l) {
  __builtin_amdgcn_global_load_lds((__attribute__((address_space(1))) const void*)g,
                                   (__attribute__((address_space(3))) void*)l, 16, 0, 0);
}

__device__ __forceinline__ unsigned short f2bf(float f) {
  unsigned u = __builtin_bit_cast(unsigned, f);
  u += 0x7fffu + ((u >> 16) & 1u);
  return (unsigned short)(u >> 16);
}
__device__ __forceinline__ float bf2f(unsigned short h) {
  unsigned u = ((unsigned)h) << 16;
  return __builtin_bit_cast(float, u);
}

// ------- casts needed BEFORE the QKV GEMM (x, wqkv, wvkv, vis) -------------
struct CastPack {
  const float* s[6];
  unsigned short* d[6];
  int n4[6];
};
__global__ void k_cast_all(CastPack p) {
  const int tid0 = blockIdx.x * blockDim.x + threadIdx.x;
  const int stride = gridDim.x * blockDim.x;
#pragma unroll 1
  for (int seg = 0; seg < 6; ++seg) {
    const float4* __restrict__ src = reinterpret_cast<const float4*>(p.s[seg]);
    ushort4* __restrict__ dst = reinterpret_cast<ushort4*>(p.d[seg]);
    const int n4 = p.n4[seg];
    for (int i = tid0; i < n4; i += stride) {
      float4 v = src[i];
      ushort4 o;
      o.x = f2bf(v.x); o.y = f2bf(v.y); o.z = f2bf(v.z); o.w = f2bf(v.w);
      dst[i] = o;
    }
  }
}

__device__ __forceinline__ void storeC(float* C, size_t i, float v) { C[i] = v; }
__device__ __forceinline__ void storeC(unsigned short* C, size_t i, float v) { C[i] = f2bf(v); }

// ------- merged QKV + vision GEMM (m97 128² structure) + wo-cast tail ------
// blocks 0..671: GEMM tiles (640 QKV + 32 vision, bijective XCD swizzle).
// blocks 672..927: grid-stride cast of wo f32->bf16 — memory-only work that
// backfills CUs as gen-1 GEMM blocks retire, using the GEMM's idle HBM
// bandwidth. wo isn't needed until the out-projection.
__global__ __launch_bounds__(256) void k_gemm_qv(
    const unsigned short* __restrict__ xb,
    const unsigned short* __restrict__ wqkvb,
    unsigned short* __restrict__ qkv,
    const unsigned short* __restrict__ visb,
    const unsigned short* __restrict__ wvkvb,
    unsigned short* __restrict__ vkvb,
    const float* __restrict__ wo_f32,
    unsigned short* __restrict__ wob) {
  __shared__ __align__(16) unsigned short lA[128 * 64];
  __shared__ __align__(16) unsigned short lB[128 * 64];
  const int orig = (int)blockIdx.x;

  if (orig >= 672) {  // ---- wo cast tail ----
    const float4* __restrict__ src = reinterpret_cast<const float4*>(wo_f32);
    ushort4* __restrict__ dst = reinterpret_cast<ushort4*>(wob);
    const int n4 = 4096 * 4096 / 4;
    const int stride = 256 * 256;
    for (int i = (orig - 672) * 256 + (int)threadIdx.x; i < n4; i += stride) {
      float4 v = src[i];
      ushort4 o;
      o.x = f2bf(v.x); o.y = f2bf(v.y); o.z = f2bf(v.z); o.w = f2bf(v.w);
      dst[i] = o;
    }
    return;
  }

  const int tid = threadIdx.x;
  const int w = tid >> 6, l = tid & 63;
  const int tile = (orig & 7) * 84 + (orig >> 3);   // bijective, 672 = 8*84

  const unsigned short* A;
  const unsigned short* B;
  unsigned short* C;
  int K, N, m0, n0;
  if (tile < 640) {
    A = xb; B = wqkvb; C = qkv; K = 4096; N = 5120;
    m0 = (tile & 15) * 128;
    n0 = (tile >> 4) * 128;
  } else {
    int v = tile - 640;
    A = visb; B = wvkvb; C = vkvb; K = 768; N = 1024;
    m0 = (v & 3) * 128;
    n0 = (v >> 2) * 128;
  }
  const int wm = (w >> 1) * 64, wn = (w & 1) * 64;

  f32x4 acc[4][4];
#pragma unroll
  for (int i = 0; i < 4; ++i)
#pragma unroll
    for (int j = 0; j < 4; ++j) acc[i][j] = f32x4{0.f, 0.f, 0.f, 0.f};

  char* lAc = (char*)lA;
  char* lBc = (char*)lB;

  for (int k0 = 0; k0 < K; k0 += 64) {
#pragma unroll
    for (int p = 0; p < 4; ++p) {
      int r = (w * 4 + p) * 8 + (l >> 3);
      int c = (l & 7) ^ (r & 7);
      gload_lds16(A + (size_t)(m0 + r) * K + k0 + c * 8, lAc + (w * 4 + p) * 1024);
      gload_lds16(B + (size_t)(n0 + r) * K + k0 + c * 8, lBc + (w * 4 + p) * 1024);
    }
    __syncthreads();
#pragma unroll
    for (int kk = 0; kk < 2; ++kk) {
      bf16x8 af[4], bfr[4];
#pragma unroll
      for (int i = 0; i < 4; ++i) {
        int r = wm + i * 16 + (l & 15);
        int slot = (kk * 4 + (l >> 4)) ^ (r & 7);
        af[i] = *(const bf16x8*)(lAc + r * 128 + slot * 16);
      }
#pragma unroll
      for (int j = 0; j < 4; ++j) {
        int r = wn + j * 16 + (l & 15);
        int slot = (kk * 4 + (l >> 4)) ^ (r & 7);
        bfr[j] = *(const bf16x8*)(lBc + r * 128 + slot * 16);
      }
#pragma unroll
      for (int i = 0; i < 4; ++i)
#pragma unroll
        for (int j = 0; j < 4; ++j)
          acc[i][j] = __builtin_amdgcn_mfma_f32_16x16x32_bf16(af[i], bfr[j], acc[i][j], 0, 0, 0);
    }
    __syncthreads();
  }

#pragma unroll
  for (int i = 0; i < 4; ++i)
#pragma unroll
    for (int j = 0; j < 4; ++j) {
      int row = m0 + wm + i * 16 + (l >> 4) * 4;
      int col = n0 + wn + j * 16 + (l & 15);
#pragma unroll
      for (int r = 0; r < 4; ++r)
        storeC(C, (size_t)(row + r) * N + col, acc[i][j][r]);
    }
}

// ---------------- 256x128 pipelined GEMM, single-barrier phases ------------
template <typename OutT>
__global__ __launch_bounds__(512) void k_gemm256x128(
    const unsigned short* __restrict__ A,
    const unsigned short* __restrict__ B,
    OutT* __restrict__ C,
    int M, int N, int K) {
  __shared__ __align__(16) unsigned short lA[2][2][256][32];
  __shared__ __align__(16) unsigned short lB[2][2][128][32];
  const int tid = threadIdx.x;
  const int w = tid >> 6, l = tid & 63;
  const int wr = w >> 2, wc = w & 3;
  const int lq = l & 15, g = l >> 4;
  const int fslot = (g ^ ((lq >> 1) & 3)) << 3;

  const int gm = M >> 8, gn = N >> 7;
  const int L = (int)blockIdx.x;
  const int xcd = L & 7, slot = L >> 3;
  const int m0 = (slot % gm) * 256;
  const int n0 = (xcd * (gn >> 3) + slot / gm) * 128;

  const unsigned short* Ap = A + (size_t)m0 * K;
  const unsigned short* Bp = B + (size_t)n0 * K;

  f32x4 acc[8][2];
#pragma unroll
  for (int i = 0; i < 8; ++i)
#pragma unroll
    for (int j = 0; j < 2; ++j) acc[i][j] = f32x4{0.f, 0.f, 0.f, 0.f};

  auto stageA = [&](unsigned short* lbase, int kcol) {
#pragma unroll
    for (int p = 0; p < 2; ++p) {
      int R = w * 32 + p * 16;
      int row = R + (l >> 2);
      int cc = ((l & 3) ^ ((l >> 3) & 3)) << 3;
      gload_lds16(Ap + (size_t)row * K + kcol + cc, lbase + R * 32);
    }
  };
  auto stageB = [&](unsigned short* lbase, int kcol) {
    int R = w * 16;
    int row = R + (l >> 2);
    int cc = ((l & 3) ^ ((l >> 3) & 3)) << 3;
    gload_lds16(Bp + (size_t)row * K + kcol + cc, lbase + R * 32);
  };

  const int nt = K >> 6;

  stageB(&lB[0][0][0][0], 0);
  stageA(&lA[0][0][0][0], 0);
  stageB(&lB[0][1][0][0], 32);
  stageA(&lA[0][1][0][0], 32);
  stageB(&lB[1][0][0][0], 64);
  stageA(&lA[1][0][0][0], 64);
  asm volatile("s_waitcnt vmcnt(3)" ::: "memory");
  __builtin_amdgcn_s_barrier();

  bf16x8 bfr[2], a[8];

  for (int T = 0; T < nt; ++T) {
    const int bf = T & 1, nb = bf ^ 1;

    // ---- phase 1: kk0 ----
#pragma unroll
    for (int nf = 0; nf < 2; ++nf)
      bfr[nf] = *(const bf16x8*)&lB[bf][0][wc * 32 + nf * 16 + lq][fslot];
#pragma unroll
    for (int mf = 0; mf < 8; ++mf)
      a[mf] = *(const bf16x8*)&lA[bf][0][wr * 128 + mf * 16 + lq][fslot];
    if (T + 1 < nt) {
      stageA(&lA[nb][1][0][0], ((T + 1) << 6) + 32);
      stageB(&lB[nb][1][0][0], ((T + 1) << 6) + 32);
    }
    asm volatile("s_waitcnt lgkmcnt(0)" ::: "memory");
    __builtin_amdgcn_s_setprio(1);
#pragma unroll
    for (int mf = 0; mf < 8; ++mf)
#pragma unroll
      for (int nf = 0; nf < 2; ++nf)
        acc[mf][nf] = __builtin_amdgcn_mfma_f32_16x16x32_bf16(a[mf], bfr[nf], acc[mf][nf], 0, 0, 0);
    __builtin_amdgcn_s_setprio(0);
    __builtin_amdgcn_s_barrier();

    // ---- phase 2: kk1 ----
#pragma unroll
    for (int nf = 0; nf < 2; ++nf)
      bfr[nf] = *(const bf16x8*)&lB[bf][1][wc * 32 + nf * 16 + lq][fslot];
#pragma unroll
    for (int mf = 0; mf < 8; ++mf)
      a[mf] = *(const bf16x8*)&lA[bf][1][wr * 128 + mf * 16 + lq][fslot];
    if (T + 2 < nt) {
      stageA(&lA[bf][0][0][0], (T + 2) << 6);
      stageB(&lB[bf][0][0][0], (T + 2) << 6);
    }
    asm volatile("s_waitcnt lgkmcnt(0)" ::: "memory");
    __builtin_amdgcn_s_setprio(1);
#pragma unroll
    for (int mf = 0; mf < 8; ++mf)
#pragma unroll
      for (int nf = 0; nf < 2; ++nf)
        acc[mf][nf] = __builtin_amdgcn_mfma_f32_16x16x32_bf16(a[mf], bfr[nf], acc[mf][nf], 0, 0, 0);
    __builtin_amdgcn_s_setprio(0);
    if (T < nt - 2)
      asm volatile("s_waitcnt vmcnt(3)" ::: "memory");
    else if (T == nt - 2)
      asm volatile("s_waitcnt vmcnt(0)" ::: "memory");
    __builtin_amdgcn_s_barrier();
  }

#pragma unroll
  for (int mf = 0; mf < 8; ++mf)
#pragma unroll
    for (int nf = 0; nf < 2; ++nf) {
      int row = m0 + wr * 128 + mf * 16 + g * 4;
      int col = n0 + wc * 32 + nf * 16 + lq;
#pragma unroll
      for (int r = 0; r < 4; ++r)
        storeC(C, (size_t)(row + r) * N + col, acc[mf][nf][r]);
    }
}

// ------- post pass: build K (+RoPE) and build V^T ---------------------------
__global__ void k_post(const unsigned short* __restrict__ qkv,   // [2048][5120]
                       const unsigned short* __restrict__ vkv,   // [512][1024]
                       const float* __restrict__ cosT, const float* __restrict__ sinT,
                       unsigned short* __restrict__ k_all,  // [8][1280][128]
                       unsigned short* __restrict__ v_t) {  // [8][128][1280]
  int idx = blockIdx.x * blockDim.x + threadIdx.x;
  if (idx < 655360) {
    int i = idx;
    int d0 = i & 63;
    int t = (i >> 6) % 1280;
    int bg = i / (64 * 1280);
    int b = bg >> 2, g = bg & 3;
    float a, bb;
    if (t < 256) {
      const unsigned short* src = vkv + (size_t)(b * 256 + t) * 1024 + g * 128;
      a = bf2f(src[d0]); bb = bf2f(src[d0 + 64]);
    } else {
      const unsigned short* src = qkv + (size_t)(b * 1024 + t - 256) * 5120 + 4096 + g * 128;
      a = bf2f(src[d0]); bb = bf2f(src[d0 + 64]);
    }
    float c0 = cosT[t * 128 + d0], s0 = sinT[t * 128 + d0];
    float c1 = cosT[t * 128 + d0 + 64], s1 = sinT[t * 128 + d0 + 64];
    unsigned short* dst = k_all + ((size_t)bg * 1280 + t) * 128;
    dst[d0] = f2bf(a * c0 - bb * s0);
    dst[d0 + 64] = f2bf(bb * c1 + a * s1);
  } else {
    int i = idx - 655360;
    int t = i % 1280;
    int d = (i / 1280) & 127;
    int bg = i / (1280 * 128);
    int b = bg >> 2, g = bg & 3;
    unsigned short v;
    if (t < 256) v = vkv[(size_t)(b * 256 + t) * 1024 + 512 + g * 128 + d];
    else         v = qkv[(size_t)(b * 1024 + t - 256) * 5120 + 4608 + g * 128 + d];
    v_t[(size_t)bg * 128 * 1280 + (size_t)d * 1280 + t] = v;
  }
}

// --------- flash attention: paired q-tiles + on-the-fly RoPE(Q) ------------
__global__ __launch_bounds__(256) void k_attn(
    const unsigned short* __restrict__ qr,     // [2048][5120] un-roped (cols 0..4095)
    const unsigned short* __restrict__ k_all,  // [8][1280][128]
    const unsigned short* __restrict__ v_t,    // [8][128][1280]
    const float* __restrict__ cosT, const float* __restrict__ sinT,
    unsigned short* __restrict__ attn) {       // [2048][4096]
  __shared__ __align__(16) unsigned short lK[2][64 * 128];
  __shared__ __align__(16) unsigned short lV[2][128 * 64];
  __shared__ __align__(16) unsigned short lPT[4][16][72];

  const int tid = threadIdx.x, w = tid >> 6, l = tid & 63;
  const int lq = l & 15, g = l >> 4;
  const int qpair = blockIdx.x;
  const int h = blockIdx.y, b = blockIdx.z;
  const int bg = b * 4 + (h >> 3);
  const unsigned short* kg = k_all + (size_t)bg * 1280 * 128;
  const unsigned short* vg = v_t + (size_t)bg * 128 * 1280;

  char* lKc = (char*)lK;
  char* lVc = (char*)lV;
  char* pbuf = (char*)&lPT[w][0][0];

  auto stage = [&](int t0, int bufsel) {
#pragma unroll
    for (int p = 0; p < 4; ++p) {  // K tile [64][128]
      int r = (w * 4 + p) * 4 + (l >> 4);
      int c = (l & 15) ^ (r & 7);
      gload_lds16(kg + (size_t)(t0 + r) * 128 + c * 8,
                  lKc + bufsel * 16384 + (w * 4 + p) * 1024);
    }
#pragma unroll
    for (int p = 0; p < 4; ++p) {  // V tile [128][64]
      int d = (w * 4 + p) * 8 + (l >> 3);
      int c = (l & 7) ^ (d & 7);
      gload_lds16(vg + (size_t)d * 1280 + t0 + c * 8,
                  lVc + bufsel * 16384 + (w * 4 + p) * 1024);
    }
  };

  int buf = 0;
#pragma unroll 1
  for (int half = 0; half < 2; ++half) {
    const int qb = (half ? (15 - qpair) : qpair) * 64;
    const int qrow_l = qb + w * 16 + lq;
    const int nIter = (qb + 320) >> 6;

    bf16x8 aq[4];
    {
      int row = qb + w * 16 + lq;
      const unsigned short* p = qr + (size_t)(b * 1024 + row) * 5120 + h * 128 + g * 8;
      bf16x8 r0 = *(const bf16x8*)(p);
      bf16x8 r1 = *(const bf16x8*)(p + 32);
      bf16x8 r2 = *(const bf16x8*)(p + 64);
      bf16x8 r3 = *(const bf16x8*)(p + 96);
      const float* cp = cosT + (size_t)row * 128;
      const float* sp = sinT + (size_t)row * 128;
      const float sc = 0.08838834764831845f;  // 128^-0.5
#pragma unroll
      for (int j = 0; j < 8; ++j) {
        int d0 = g * 8 + j;
        float a0 = bf2f((unsigned short)r0[j]), b0 = bf2f((unsigned short)r2[j]);
        aq[0][j] = (short)f2bf((a0 * cp[d0] - b0 * sp[d0]) * sc);
        aq[2][j] = (short)f2bf((b0 * cp[d0 + 64] + a0 * sp[d0 + 64]) * sc);
        int d1 = 32 + g * 8 + j;
        float a1 = bf2f((unsigned short)r1[j]), b1 = bf2f((unsigned short)r3[j]);
        aq[1][j] = (short)f2bf((a1 * cp[d1] - b1 * sp[d1]) * sc);
        aq[3][j] = (short)f2bf((b1 * cp[d1 + 64] + a1 * sp[d1 + 64]) * sc);
      }
    }

    f32x4 o[8];
#pragma unroll
    for (int i = 0; i < 8; ++i) o[i] = f32x4{0.f, 0.f, 0.f, 0.f};
    float mr = -1e30f;
    float lrp = 0.f;

    stage(0, buf);
    __syncthreads();

    for (int it = 0; it < nIter; ++it) {
      const int t0 = it << 6;
      if (it + 1 < nIter) stage(t0 + 64, buf ^ 1);

      const char* kbase = lKc + buf * 16384;
      const char* vbase = lVc + buf * 16384;

      f32x4 sT[4];
      __builtin_amdgcn_s_setprio(1);
#pragma unroll
      for (int sub = 0; sub < 4; ++sub) {
        f32x4 s4 = {0.f, 0.f, 0.f, 0.f};
        int krow = sub * 16 + lq;
        const char* kb = kbase + krow * 256;
#pragma unroll
        for (int kk = 0; kk < 4; ++kk) {
          int slot = (kk * 4 + g) ^ (krow & 7);
          bf16x8 kf = *(const bf16x8*)(kb + slot * 16);
          s4 = __builtin_amdgcn_mfma_f32_16x16x32_bf16(kf, aq[kk], s4, 0, 0, 0);
        }
        sT[sub] = s4;
      }
      __builtin_amdgcn_s_setprio(0);

      if (t0 + 63 > qb + w * 16 + 256) {
#pragma unroll
        for (int sub = 0; sub < 4; ++sub)
#pragma unroll
          for (int r = 0; r < 4; ++r) {
            int t = t0 + sub * 16 + 4 * g + r;
            if (t > qrow_l + 256) sT[sub][r] = -1e30f;
          }
      }

      float pm = fmaxf(fmaxf(fmaxf(sT[0][0], sT[0][1]), fmaxf(sT[0][2], sT[0][3])),
                       fmaxf(fmaxf(sT[1][0], sT[1][1]), fmaxf(sT[1][2], sT[1][3])));
      pm = fmaxf(pm, fmaxf(fmaxf(fmaxf(sT[2][0], sT[2][1]), fmaxf(sT[2][2], sT[2][3])),
                           fmaxf(fmaxf(sT[3][0], sT[3][1]), fmaxf(sT[3][2], sT[3][3]))));
      pm = fmaxf(pm, __shfl_xor(pm, 16));
      pm = fmaxf(pm, __shfl_xor(pm, 32));

      if (!__all(pm <= mr + 8.0f)) {
        float mnew = fmaxf(mr, pm);
        float scl = __expf(mr - mnew);
        mr = mnew;
        lrp *= scl;
        float s0 = __shfl(scl, 4 * g + 0);
        float s1 = __shfl(scl, 4 * g + 1);
        float s2 = __shfl(scl, 4 * g + 2);
        float s3 = __shfl(scl, 4 * g + 3);
#pragma unroll
        for (int cs = 0; cs < 8; ++cs) {
          o[cs][0] *= s0; o[cs][1] *= s1; o[cs][2] *= s2; o[cs][3] *= s3;
        }
      }

#pragma unroll
      for (int sub = 0; sub < 4; ++sub) {
        float p0 = __expf(sT[sub][0] - mr);
        float p1 = __expf(sT[sub][1] - mr);
        float p2 = __expf(sT[sub][2] - mr);
        float p3 = __expf(sT[sub][3] - mr);
        lrp += (p0 + p1) + (p2 + p3);
        unsigned pk0, pk1;
        asm("v_cvt_pk_bf16_f32 %0, %1, %2" : "=v"(pk0) : "v"(p0), "v"(p1));
        asm("v_cvt_pk_bf16_f32 %0, %1, %2" : "=v"(pk1) : "v"(p2), "v"(p3));
        int c = (2 * sub + (g >> 1)) ^ (lq & 7);
        *(uint2*)(pbuf + lq * 144 + c * 16 + (g & 1) * 8) = make_uint2(pk0, pk1);
      }

      asm volatile("s_waitcnt lgkmcnt(0)" ::: "memory");

      bf16x8 pa0 = *(const bf16x8*)(pbuf + lq * 144 + ((g ^ (lq & 7)) * 16));
      bf16x8 pa1 = *(const bf16x8*)(pbuf + lq * 144 + (((4 + g) ^ (lq & 7)) * 16));

      __builtin_amdgcn_s_setprio(1);
#pragma unroll
      for (int cs = 0; cs < 8; ++cs) {
        int drow = cs * 16 + lq;
        const char* vb = vbase + drow * 128;
        int s0i = g ^ (drow & 7);
        int s1i = (4 + g) ^ (drow & 7);
        bf16x8 v0 = *(const bf16x8*)(vb + s0i * 16);
        bf16x8 v1 = *(const bf16x8*)(vb + s1i * 16);
        o[cs] = __builtin_amdgcn_mfma_f32_16x16x32_bf16(pa0, v0, o[cs], 0, 0, 0);
        o[cs] = __builtin_amdgcn_mfma_f32_16x16x32_bf16(pa1, v1, o[cs], 0, 0, 0);
      }
      __builtin_amdgcn_s_setprio(0);

      __syncthreads();
      buf ^= 1;
    }

    lrp += __shfl_xor(lrp, 16);
    lrp += __shfl_xor(lrp, 32);
    float inv = 1.0f / lrp;
    float invr[4];
    invr[0] = __shfl(inv, 4 * g + 0);
    invr[1] = __shfl(inv, 4 * g + 1);
    invr[2] = __shfl(inv, 4 * g + 2);
    invr[3] = __shfl(inv, 4 * g + 3);
#pragma unroll
    for (int cs = 0; cs < 8; ++cs)
#pragma unroll
      for (int r = 0; r < 4; ++r) {
        int row = qb + w * 16 + 4 * g + r;
        attn[(size_t)(b * 1024 + row) * 4096 + h * 128 + cs * 16 + lq] =
            f2bf(o[cs][r] * invr[r]);
      }
  }
}

// ---------------- launcher ----------------
extern "C" void kernel_launch(void* const* d_in, const int* in_sizes, int n_in,
                              void* d_out, int out_size, void* d_ws, size_t ws_size,
                              hipStream_t stream) {
  const float* x    = (const float*)d_in[0];
  const float* vis  = (const float*)d_in[1];
  const float* wq   = (const float*)d_in[2];
  const float* wk   = (const float*)d_in[3];
  const float* wv   = (const float*)d_in[4];
  const float* wo   = (const float*)d_in[5];
  const float* wvkv = (const float*)d_in[6];
  const float* cosT = (const float*)d_in[7];
  const float* sinT = (const float*)d_in[8];
  float* out = (float*)d_out;
  char* ws = (char*)d_ws;

  size_t off = 0;
  auto alloc = [&](size_t b) { size_t r = off; off += (b + 255) & ~(size_t)255; return r; };
  unsigned short* wqkvb = (unsigned short*)(ws + alloc((size_t)5120 * 4096 * 2));  // wq|wk|wv
  unsigned short* wob   = (unsigned short*)(ws + alloc((size_t)4096 * 4096 * 2));
  unsigned short* wvkvb = (unsigned short*)(ws + alloc((size_t)1024 * 768 * 2));
  unsigned short* visb  = (unsigned short*)(ws + alloc((size_t)512 * 768 * 2));
  unsigned short* xb    = (unsigned short*)(ws + alloc((size_t)2048 * 4096 * 2));
  unsigned short* qkv   = (unsigned short*)(ws + alloc((size_t)2048 * 5120 * 2));
  unsigned short* vkvb  = (unsigned short*)(ws + alloc((size_t)512 * 1024 * 2));
  unsigned short* kall  = (unsigned short*)(ws + alloc((size_t)8 * 1280 * 128 * 2));
  unsigned short* vt    = (unsigned short*)(ws + alloc((size_t)8 * 128 * 1280 * 2));
  unsigned short* attnb = xb;  // x is dead after the QKV projection; reuse
  if (ws_size < off) return;

  CastPack cp;
  cp.s[0] = x;    cp.d[0] = xb;                           cp.n4[0] = 2048 * 4096 / 4;
  cp.s[1] = wq;   cp.d[1] = wqkvb;                        cp.n4[1] = 4096 * 4096 / 4;
  cp.s[2] = wk;   cp.d[2] = wqkvb + (size_t)4096 * 4096;  cp.n4[2] = 512 * 4096 / 4;
  cp.s[3] = wv;   cp.d[3] = wqkvb + (size_t)4608 * 4096;  cp.n4[3] = 512 * 4096 / 4;
  cp.s[4] = wvkv; cp.d[4] = wvkvb;                        cp.n4[4] = 1024 * 768 / 4;
  cp.s[5] = vis;  cp.d[5] = visb;                         cp.n4[5] = 512 * 768 / 4;
  k_cast_all<<<dim3(2048), dim3(256), 0, stream>>>(cp);

  // merged QKV + vision projections (672 GEMM blocks) + wo-cast tail (256)
  k_gemm_qv<<<dim3(928), dim3(256), 0, stream>>>(xb, wqkvb, qkv, visb, wvkvb, vkvb, wo, wob);

  // build K (+RoPE) and V^T (Q rope is fused into attention)
  k_post<<<dim3(7680), dim3(256), 0, stream>>>(qkv, vkvb, cosT, sinT, kall, vt);

  // paired-tile attention: 512 blocks, uniform work, on-the-fly Q rope
  k_attn<<<dim3(8, 32, 2), dim3(256), 0, stream>>>(qkv, kall, vt, cosT, sinT, attnb);

  // out projection (single-barrier pipelined 256x128, 256 blocks)
  k_gemm256x128<float><<<dim3(256), dim3(512), 0, stream>>>(attnb, wob, out, 2048, 4096, 4096);
}